// Round 4
// baseline (396.873 us; speedup 1.0000x reference)
//
#include <hip/hip_runtime.h>

typedef unsigned short u16;
typedef unsigned int u32;
typedef unsigned long long u64;
typedef __bf16 bf16x8 __attribute__((ext_vector_type(8)));
typedef float f32x4 __attribute__((ext_vector_type(4)));
typedef float f32x16 __attribute__((ext_vector_type(16)));
typedef u32 u32x4 __attribute__((ext_vector_type(4)));

#define DEV static __device__ __forceinline__

constexpr int B_ = 2, L_ = 2048, H_ = 2048;
constexpr int NH_ = 16, HD_ = 128, RD_ = 64;
constexpr int QR_ = 768, KVR_ = 512;
constexpr int BL_ = B_ * L_;          // 4096 tokens
constexpr int QKD_ = HD_ + RD_;       // 192
constexpr int QKS_ = NH_ * QKD_;      // 3072
constexpr int NHHD_ = NH_ * HD_;      // 2048

DEV u16 f2bf(float f) {
    u32 u = __builtin_bit_cast(u32, f);
    u32 r = (u + 0x7fffu + ((u >> 16) & 1u)) >> 16;
    return (u16)r;
}
DEV float bf2f(u16 h) {
    u32 u = ((u32)h) << 16;
    return __builtin_bit_cast(float, u);
}
DEV u32 cvtpk(float lo, float hi) {
    u32 r;
    asm("v_cvt_pk_bf16_f32 %0, %1, %2" : "=v"(r) : "v"(lo), "v"(hi));
    return r;
}
DEV void plswap(u32& a, u32& b) {
    asm("v_permlane32_swap_b32 %0, %1" : "+v"(a), "+v"(b));
}
DEV bf16x8 ld8(const u16* p) { return __builtin_bit_cast(bf16x8, *(const u32x4*)p); }
DEV f32x4 mfma16(bf16x8 a, bf16x8 b, f32x4 c) {
    return __builtin_amdgcn_mfma_f32_16x16x32_bf16(a, b, c, 0, 0, 0);
}
DEV f32x16 mfma32(bf16x8 a, bf16x8 b, f32x16 c) {
    return __builtin_amdgcn_mfma_f32_32x32x16_bf16(a, b, c, 0, 0, 0);
}
DEV void gload16(const void* g, void* l) {
    __builtin_amdgcn_global_load_lds((const __attribute__((address_space(1))) void*)g,
                                     (__attribute__((address_space(3))) void*)l, 16, 0, 0);
}

// ---------------- elementwise cast: f32 -> bf16, 4 elems/thread ----------------
__global__ __launch_bounds__(256) void cast_bf16_kernel(const float* __restrict__ src,
                                                        u16* __restrict__ dst, int n4) {
    int i = blockIdx.x * 256 + threadIdx.x;
    if (i >= n4) return;
    float4 v = ((const float4*)src)[i];
    u64 pk = (u64)f2bf(v.x) | ((u64)f2bf(v.y) << 16) | ((u64)f2bf(v.z) << 32) | ((u64)f2bf(v.w) << 48);
    ((u64*)dst)[i] = pk;
}

// ------------- cast + transpose: src (K x N) f32 -> dst (dstN x K) bf16, zero-pad rows >= N -------------
__global__ __launch_bounds__(256) void cast_transpose(const float* __restrict__ src, u16* __restrict__ dst,
                                                      int K, int N, int dstN) {
    __shared__ float tile[32][33];
    int n0 = blockIdx.x * 32, k0 = blockIdx.y * 32;
    int tx = threadIdx.x & 31, ty = threadIdx.x >> 5;  // 32 x 8
#pragma unroll
    for (int i = 0; i < 4; ++i) {
        int kk = ty + i * 8;
        int n = n0 + tx;
        tile[kk][tx] = (n < N) ? src[(size_t)(k0 + kk) * N + n] : 0.f;
    }
    __syncthreads();
#pragma unroll
    for (int i = 0; i < 4; ++i) {
        int nn = ty + i * 8;
        dst[(size_t)(n0 + nn) * K + k0 + tx] = f2bf(tile[tx][nn]);
    }
}

// ---------------- GEMM (m97 structure): C = A(M x K, lda) * Bt(N x K)^T ----------------
template <int OUTF32>
__global__ __launch_bounds__(256, 2) void gemm_bt(const u16* __restrict__ A, int lda,
                                                  const u16* __restrict__ Bt,
                                                  void* __restrict__ Cv, int ldc, int K) {
    __shared__ u16 As[128 * 32];
    __shared__ u16 Bs[128 * 32];
    const int tid = threadIdx.x;
    const int l = tid & 63, w = tid >> 6;
    const int l15 = l & 15, g = l >> 4;
    const int wr = w >> 1, wc = w & 1;
    const int bm = blockIdx.y * 128, bn = blockIdx.x * 128;

    const f32x4 zero = {0.f, 0.f, 0.f, 0.f};
    f32x4 acc[4][4];
#pragma unroll
    for (int m = 0; m < 4; ++m)
#pragma unroll
        for (int n = 0; n < 4; ++n) acc[m][n] = zero;

    const int ar0 = w * 32 + (l >> 2), kc8 = (l & 3) * 8;
    const u16* aptr = A + (size_t)(bm + ar0) * lda + kc8;
    const u16* aptr2 = A + (size_t)(bm + ar0 + 16) * lda + kc8;
    const u16* bptr = Bt + (size_t)(bn + ar0) * K + kc8;
    const u16* bptr2 = Bt + (size_t)(bn + ar0 + 16) * K + kc8;
    u16* asl = As + w * 1024;
    u16* bsl = Bs + w * 1024;

    const int nK = K / 32;
    for (int kt = 0; kt < nK; ++kt) {
        const int ko = kt * 32;
        __syncthreads();
        gload16(aptr + ko, asl);
        gload16(aptr2 + ko, asl + 512);
        gload16(bptr + ko, bsl);
        gload16(bptr2 + ko, bsl + 512);
        __syncthreads();
        bf16x8 af[4], bfr[4];
#pragma unroll
        for (int m = 0; m < 4; ++m)
            af[m] = ld8(As + (wr * 64 + m * 16 + l15) * 32 + g * 8);
#pragma unroll
        for (int n = 0; n < 4; ++n)
            bfr[n] = ld8(Bs + (wc * 64 + n * 16 + l15) * 32 + g * 8);
#pragma unroll
        for (int m = 0; m < 4; ++m)
#pragma unroll
            for (int n = 0; n < 4; ++n) acc[m][n] = mfma16(af[m], bfr[n], acc[m][n]);
    }
#pragma unroll
    for (int m = 0; m < 4; ++m)
#pragma unroll
        for (int n = 0; n < 4; ++n)
#pragma unroll
            for (int r = 0; r < 4; ++r) {
                int row = bm + wr * 64 + m * 16 + g * 4 + r;
                int col = bn + wc * 64 + n * 16 + l15;
                if (OUTF32)
                    ((float*)Cv)[(size_t)row * ldc + col] = acc[m][n][r];
                else
                    ((u16*)Cv)[(size_t)row * ldc + col] = f2bf(acc[m][n][r]);
            }
}

// ------------- pack: src [BL][2048] (row stride S) -> dst [BL][3072] at h*192 + d (d<128) -------------
__global__ __launch_bounds__(256) void pack_content(const u16* __restrict__ src, int S,
                                                    u16* __restrict__ dst) {
    size_t i = (size_t)blockIdx.x * 256 + threadIdx.x;  // BL*2048/8
    int token = (int)(i >> 8), c = (int)(i & 255);
    int h = c >> 4, d8 = c & 15;
    u32x4 v = *(const u32x4*)(src + (size_t)token * S + c * 8);
    *(u32x4*)(dst + (size_t)token * QKS_ + h * QKD_ + d8 * 8) = v;
}

// ------------- RoPE on q_rope (cols h*64+i at stride S), write into q at h*192+128+i -------------
__global__ __launch_bounds__(256) void rope_q_kernel(const u16* __restrict__ src, int S,
                                                     u16* __restrict__ dst) {
    int idx = blockIdx.x * 256 + threadIdx.x;  // BL*NH*32
    int token = idx >> 9;
    int r = idx & 511;
    int h = r >> 5, i = r & 31;
    int pos = token & (L_ - 1);
    float ang = (float)pos * exp2f((float)i * (-13.287712379549449f / 32.f));
    float c = cosf(ang), s = sinf(ang);
    float x1 = bf2f(src[(size_t)token * S + h * 64 + i]);
    float x2 = bf2f(src[(size_t)token * S + h * 64 + i + 32]);
    u16* base = dst + (size_t)token * QKS_ + h * QKD_ + HD_;
    base[i] = f2bf(x1 * c - x2 * s);
    base[i + 32] = f2bf(x2 * c + x1 * s);
}

// ------------- RoPE on k_rope (64 cols at stride S) + broadcast to all heads of k -------------
__global__ __launch_bounds__(256) void rope_k_kernel(const u16* __restrict__ src, int S,
                                                     u16* __restrict__ dst) {
    int idx = blockIdx.x * 256 + threadIdx.x;  // BL*32
    int token = idx >> 5, i = idx & 31;
    int pos = token & (L_ - 1);
    float ang = (float)pos * exp2f((float)i * (-13.287712379549449f / 32.f));
    float c = cosf(ang), s = sinf(ang);
    float x1 = bf2f(src[(size_t)token * S + i]);
    float x2 = bf2f(src[(size_t)token * S + i + 32]);
    u16 o1 = f2bf(x1 * c - x2 * s);
    u16 o2 = f2bf(x2 * c + x1 * s);
    u16* base = dst + (size_t)token * QKS_ + HD_;
#pragma unroll
    for (int h = 0; h < NH_; ++h) {
        base[h * QKD_ + i] = o1;
        base[h * QKD_ + i + 32] = o2;
    }
}

// ------------- transpose v [BL][*] (stride S) -> vt [(b*2048+col)][L] -------------
__global__ __launch_bounds__(256) void transpose_v(const u16* __restrict__ v, int S,
                                                   u16* __restrict__ vt) {
    __shared__ u16 tile[64][72];
    int cb = blockIdx.x * 64, lb = blockIdx.y * 64, b = blockIdx.z;
    int tid = threadIdx.x;
    int tr = tid >> 3, tc = (tid & 7) * 8;
#pragma unroll
    for (int i = 0; i < 2; ++i) {
        int row = tr + i * 32;
        u32x4 d = *(const u32x4*)(v + (size_t)(b * L_ + lb + row) * S + cb + tc);
        *(u32x4*)&tile[row][tc] = d;
    }
    __syncthreads();
#pragma unroll
    for (int i = 0; i < 2; ++i) {
        int col = tr + i * 32;
        u16 tmp[8];
#pragma unroll
        for (int j = 0; j < 8; ++j) tmp[j] = tile[tc + j][col];
        *(u32x4*)(vt + (size_t)(b * NHHD_ + cb + col) * L_ + lb + tc) = *(u32x4*)tmp;
    }
}

// ------------- causal flash attention, swapped-QK 32x32, paired qtiles + dbuf prefetch -------------
// VALU-diet version: raw-domain scores (scale folded into exp via fma), defer-rescale (T13),
// cvt_pk + permlane32_swap P-pack (T12), V-fragments hoisted into regs before softmax.
__global__ __launch_bounds__(256, 1) void flash_attn(const u16* __restrict__ q, const u16* __restrict__ k,
                                                     const u16* __restrict__ vt, u16* __restrict__ attn_o) {
    __shared__ __align__(16) u16 Ks[2][64 * 192];   // 2 x 24576 B
    __shared__ __align__(16) u16 Vs[2][128 * 64];   // 2 x 16384 B
    const int p = blockIdx.x, h = blockIdx.y, b = blockIdx.z;
    const int tid = threadIdx.x, w = tid >> 6, l = tid & 63;
    const int ql = l & 31, hi = l >> 5;
    const int sw = ql & 7;

    const u16* kbase = k + (size_t)(b * L_) * QKS_ + h * QKD_;
    const u16* vtbase = vt + (size_t)(b * NHHD_ + h * HD_) * L_;

    // per-lane pre-swizzled global source offsets (elements within a tile)
    int koff[6], voff[4];
#pragma unroll
    for (int j = 0; j < 6; ++j) {
        int off = j * 4096 + tid * 16;
        int row = off / 384;
        int gr = (off % 384) / 16;
        koff[j] = row * QKS_ + (gr ^ (row & 7)) * 8;
    }
#pragma unroll
    for (int j = 0; j < 4; ++j) {
        int off = j * 4096 + tid * 16;
        int row = off >> 7;
        int gr = (off >> 4) & 7;
        voff[j] = row * L_ + (gr ^ (row & 7)) * 8;
    }

    auto STAGE = [&](int buf, int kv0) {
        const u16* kb = kbase + (size_t)kv0 * QKS_;
#pragma unroll
        for (int j = 0; j < 6; ++j)
            gload16(kb + koff[j], (u16*)Ks[buf] + j * 2048 + w * 512);
        const u16* vb = vtbase + kv0;
#pragma unroll
        for (int j = 0; j < 4; ++j)
            gload16(vb + voff[j], (u16*)Vs[buf] + j * 2048 + w * 512);
    };

    constexpr float scale2 = 0.07216878364870322f * 1.4426950408889634f;  // 1/sqrt(192)*log2(e)
    constexpr float thr_raw = 8.f / scale2;   // defer-rescale threshold, raw-score domain

    for (int half = 0; half < 2; ++half) {
        const int qtile = half ? 15 - p : p;
        const int q0 = qtile * 128;
        const int qabs = q0 + w * 32 + ql;

        bf16x8 qf[12];
        {
            const u16* qrow = q + (size_t)(b * L_ + qabs) * QKS_ + h * QKD_;
#pragma unroll
            for (int c = 0; c < 12; ++c) qf[c] = ld8(qrow + c * 16 + hi * 8);
        }
        f32x16 o[4];
#pragma unroll
        for (int n = 0; n < 4; ++n)
#pragma unroll
            for (int r = 0; r < 16; ++r) o[n][r] = 0.f;
        float m2 = -1e30f, lsum = 0.f;

        const int nt = 2 * qtile + 2;
        STAGE(0, 0);
        for (int t = 0; t < nt; ++t) {
            __syncthreads();   // tile t landed, buf (t+1)&1 free
            if (t + 1 < nt) STAGE((t + 1) & 1, (t + 1) * 64);
            const u16* Kb = Ks[t & 1];
            const u16* Vb = Vs[t & 1];
            const int kv0 = t * 64;

            // QK^T (raw scores): S^T[kv][q], two 32-row halves
            f32x16 s0, s1;
#pragma unroll
            for (int r = 0; r < 16; ++r) { s0[r] = 0.f; s1[r] = 0.f; }
#pragma unroll
            for (int c = 0; c < 12; ++c) {
                int gsw = ((2 * c + hi) ^ sw) * 16;
                bf16x8 k0 = ld8((const u16*)((const char*)Kb + ql * 384 + gsw));
                bf16x8 k1 = ld8((const u16*)((const char*)Kb + (32 + ql) * 384 + gsw));
                s0 = mfma32(k0, qf[c], s0);
                s1 = mfma32(k1, qf[c], s1);
            }

            // hoist V fragments into regs (LDS latency hides under softmax VALU)
            bf16x8 vfr[4][4];
#pragma unroll
            for (int c = 0; c < 4; ++c) {
                const int gsw = ((2 * c + hi) ^ sw) * 16;
#pragma unroll
                for (int n = 0; n < 4; ++n)
                    vfr[c][n] = ld8((const u16*)((const char*)Vb + (32 * n + ql) * 128 + gsw));
            }

            // mask + row max (raw domain), two partial chains
            const bool domask = (kv0 + 63 > q0);
            float mxa = -3e38f, mxb = -3e38f;
#pragma unroll
            for (int r = 0; r < 16; ++r) {
                const int kk = (r & 3) + 8 * (r >> 2) + 4 * hi;
                float x0 = s0[r];
                float x1 = s1[r];
                if (domask) {
                    if (kv0 + kk > qabs) x0 = -3e38f;
                    if (kv0 + 32 + kk > qabs) x1 = -3e38f;
                    s0[r] = x0; s1[r] = x1;
                }
                mxa = fmaxf(mxa, x0);
                mxb = fmaxf(mxb, x1);
            }
            float mx = fmaxf(mxa, mxb);
            mx = fmaxf(mx, __shfl_xor(mx, 32));

            // defer-rescale (T13): only rescale when max grew materially
            if (__any(mx > m2 + thr_raw)) {
                const float mnew = fmaxf(m2, mx);
                const float f = exp2f((m2 - mnew) * scale2);
                m2 = mnew;
                lsum *= f;
#pragma unroll
                for (int n = 0; n < 4; ++n)
#pragma unroll
                    for (int r = 0; r < 16; ++r) o[n][r] *= f;
            }

            // P = exp2(fma(s, scale2, -m2*scale2)), two partial sums
            const float nc2 = -m2 * scale2;
            float sla = 0.f, slb = 0.f;
#pragma unroll
            for (int r = 0; r < 16; ++r) {
                float p0 = exp2f(fmaf(s0[r], scale2, nc2));
                float p1 = exp2f(fmaf(s1[r], scale2, nc2));
                s0[r] = p0; s1[r] = p1;
                sla += p0; slb += p1;
            }
            lsum += sla + slb;

            // P-pack: cvt_pk pairs + permlane32_swap half-exchange, then PV (transposed)
#pragma unroll
            for (int c = 0; c < 4; ++c) {
                const int rb = 8 * (c & 1);
                u32 a0, a1, b0, b1;
                if (c < 2) {
                    a0 = cvtpk(s0[rb + 0], s0[rb + 1]);
                    a1 = cvtpk(s0[rb + 2], s0[rb + 3]);
                    b0 = cvtpk(s0[rb + 4], s0[rb + 5]);
                    b1 = cvtpk(s0[rb + 6], s0[rb + 7]);
                } else {
                    a0 = cvtpk(s1[rb + 0], s1[rb + 1]);
                    a1 = cvtpk(s1[rb + 2], s1[rb + 3]);
                    b0 = cvtpk(s1[rb + 4], s1[rb + 5]);
                    b1 = cvtpk(s1[rb + 6], s1[rb + 7]);
                }
                plswap(a0, b0);   // a0 <- {lo:own a0, hi:lo-half b0}; b0 <- {lo:hi-half a0, hi:own b0}
                plswap(a1, b1);
                u32x4 pw = {a0, a1, b0, b1};
                bf16x8 pf = __builtin_bit_cast(bf16x8, pw);
#pragma unroll
                for (int n = 0; n < 4; ++n) o[n] = mfma32(vfr[c][n], pf, o[n]);
            }
        }

        // finalize: combine halves' sums, normalize, write O^T as [token][h*128+d]
        const float ltot = lsum + __shfl_xor(lsum, 32);
        const float inv = 1.f / ltot;
        u16* obase = attn_o + (size_t)(b * L_ + qabs) * NHHD_ + h * HD_;
#pragma unroll
        for (int n = 0; n < 4; ++n)
#pragma unroll
            for (int rg = 0; rg < 4; ++rg) {
                const int d0 = 32 * n + 8 * rg + 4 * hi;
                u32 pk0 = cvtpk(o[n][4 * rg + 0] * inv, o[n][4 * rg + 1] * inv);
                u32 pk1 = cvtpk(o[n][4 * rg + 2] * inv, o[n][4 * rg + 3] * inv);
                *(u64*)(obase + d0) = (u64)pk0 | ((u64)pk1 << 32);
            }
    }
}

extern "C" void kernel_launch(void* const* d_in, const int* in_sizes, int n_in,
                              void* d_out, int out_size, void* d_ws, size_t ws_size,
                              hipStream_t stream) {
    (void)in_sizes; (void)n_in; (void)out_size; (void)ws_size;
    const float* x = (const float*)d_in[0];
    const float* wq_down = (const float*)d_in[1];
    const float* wq_up = (const float*)d_in[2];
    const float* wq_rope = (const float*)d_in[3];
    const float* wkv_down = (const float*)d_in[4];
    const float* wk_up = (const float*)d_in[5];
    const float* wv_up = (const float*)d_in[6];
    const float* wk_rope = (const float*)d_in[7];
    const float* wo = (const float*)d_in[8];

    u16* W = (u16*)d_ws;
    size_t off = 0;
    auto alloc = [&](size_t e) { u16* p = W + off; off += (e + 127) & ~(size_t)127; return p; };

    u16* xb    = alloc((size_t)BL_ * H_);        // 4096 x 2048
    u16* Wdn   = alloc((size_t)1408 * H_);       // [768 qd | 512 kvd | 128 kr(pad)] x 2048
    u16* Wupq  = alloc((size_t)3072 * QR_);      // [2048 qu | 1024 qr] x 768
    u16* Wupkv = alloc((size_t)4096 * KVR_);     // [2048 ku | 2048 vu] x 512
    u16* Wo_t  = alloc((size_t)H_ * NHHD_);      // 2048 x 2048
    u16* C1    = alloc((size_t)BL_ * 1408);      // latents: q_lat | kv_lat | k_rope_raw
    u16* C2    = alloc((size_t)BL_ * 3072);      // q_content | q_rope_raw
    u16* C3    = alloc((size_t)BL_ * 4096);      // k_content | v
    u16* qbuf  = alloc((size_t)BL_ * QKS_);
    u16* kbuf  = alloc((size_t)BL_ * QKS_);
    u16* vt    = alloc((size_t)BL_ * NHHD_);
    u16* attn_o = alloc((size_t)BL_ * NHHD_);

    // 1. casts + fused weight transposes
    cast_bf16_kernel<<<(BL_ * H_ / 4 + 255) / 256, 256, 0, stream>>>(x, xb, BL_ * H_ / 4);
    cast_transpose<<<dim3(QR_ / 32, H_ / 32), 256, 0, stream>>>(wq_down, Wdn, H_, QR_, QR_);
    cast_transpose<<<dim3(KVR_ / 32, H_ / 32), 256, 0, stream>>>(wkv_down, Wdn + (size_t)768 * H_, H_, KVR_, KVR_);
    cast_transpose<<<dim3(128 / 32, H_ / 32), 256, 0, stream>>>(wk_rope, Wdn + (size_t)1280 * H_, H_, RD_, 128);
    cast_transpose<<<dim3(NHHD_ / 32, QR_ / 32), 256, 0, stream>>>(wq_up, Wupq, QR_, NHHD_, NHHD_);
    cast_transpose<<<dim3(1024 / 32, QR_ / 32), 256, 0, stream>>>(wq_rope, Wupq + (size_t)2048 * QR_, QR_, 1024, 1024);
    cast_transpose<<<dim3(NHHD_ / 32, KVR_ / 32), 256, 0, stream>>>(wk_up, Wupkv, KVR_, NHHD_, NHHD_);
    cast_transpose<<<dim3(NHHD_ / 32, KVR_ / 32), 256, 0, stream>>>(wv_up, Wupkv + (size_t)2048 * KVR_, KVR_, NHHD_, NHHD_);
    cast_transpose<<<dim3(NHHD_ / 32, H_ / 32), 256, 0, stream>>>(wo, Wo_t, NHHD_, H_, H_);

    // 2. fused projection GEMMs
    gemm_bt<0><<<dim3(1408 / 128, BL_ / 128), 256, 0, stream>>>(xb, H_, Wdn, C1, 1408, H_);
    gemm_bt<0><<<dim3(3072 / 128, BL_ / 128), 256, 0, stream>>>(C1, 1408, Wupq, C2, 3072, QR_);
    gemm_bt<0><<<dim3(4096 / 128, BL_ / 128), 256, 0, stream>>>(C1 + 768, 1408, Wupkv, C3, 4096, KVR_);

    // 3. assemble q, k, vt
    pack_content<<<BL_ * NHHD_ / 8 / 256, 256, 0, stream>>>(C2, 3072, qbuf);
    pack_content<<<BL_ * NHHD_ / 8 / 256, 256, 0, stream>>>(C3, 4096, kbuf);
    rope_q_kernel<<<BL_ * NH_ * 32 / 256, 256, 0, stream>>>(C2 + 2048, 3072, qbuf);
    rope_k_kernel<<<BL_ * 32 / 256, 256, 0, stream>>>(C1 + 1280, 1408, kbuf);
    transpose_v<<<dim3(NHHD_ / 64, L_ / 64, B_), 256, 0, stream>>>(C3 + 2048, 4096, vt);

    // 4. attention (paired qtiles, balanced)
    flash_attn<<<dim3(8, NH_, B_), 256, 0, stream>>>(qbuf, kbuf, vt, attn_o);

    // 5. output projection (fp32 out)
    gemm_bt<1><<<dim3(H_ / 128, BL_ / 128), 256, 0, stream>>>(attn_o, NHHD_, Wo_t, d_out, H_, NHHD_);
}

// Round 5
// 329.807 us; speedup vs baseline: 1.2034x; 1.2034x over previous
//
#include <hip/hip_runtime.h>

typedef unsigned short u16;
typedef unsigned int u32;
typedef unsigned long long u64;
typedef __bf16 bf16x8 __attribute__((ext_vector_type(8)));
typedef float f32x4 __attribute__((ext_vector_type(4)));
typedef float f32x16 __attribute__((ext_vector_type(16)));
typedef u32 u32x4 __attribute__((ext_vector_type(4)));

#define DEV static __device__ __forceinline__

constexpr int B_ = 2, L_ = 2048, H_ = 2048;
constexpr int NH_ = 16, HD_ = 128, RD_ = 64;
constexpr int QR_ = 768, KVR_ = 512;
constexpr int BL_ = B_ * L_;          // 4096 tokens
constexpr int QKD_ = HD_ + RD_;       // 192
constexpr int QKS_ = NH_ * QKD_;      // 3072
constexpr int NHHD_ = NH_ * HD_;      // 2048
constexpr int ROWS_ = B_ * NH_ * L_;  // 65536 partial rows per split
constexpr float SCALE2 = 0.07216878364870322f * 1.4426950408889634f;  // 1/sqrt(192)*log2(e)

DEV u16 f2bf(float f) {
    u32 u = __builtin_bit_cast(u32, f);
    u32 r = (u + 0x7fffu + ((u >> 16) & 1u)) >> 16;
    return (u16)r;
}
DEV float bf2f(u16 h) {
    u32 u = ((u32)h) << 16;
    return __builtin_bit_cast(float, u);
}
DEV u32 pk2(float lo, float hi) { return (u32)f2bf(lo) | ((u32)f2bf(hi) << 16); }
DEV bf16x8 ld8(const u16* p) { return __builtin_bit_cast(bf16x8, *(const u32x4*)p); }
DEV f32x4 mfma16(bf16x8 a, bf16x8 b, f32x4 c) {
    return __builtin_amdgcn_mfma_f32_16x16x32_bf16(a, b, c, 0, 0, 0);
}
DEV f32x16 mfma32(bf16x8 a, bf16x8 b, f32x16 c) {
    return __builtin_amdgcn_mfma_f32_32x32x16_bf16(a, b, c, 0, 0, 0);
}
DEV void gload16(const void* g, void* l) {
    __builtin_amdgcn_global_load_lds((const __attribute__((address_space(1))) void*)g,
                                     (__attribute__((address_space(3))) void*)l, 16, 0, 0);
}

// ---------------- elementwise cast: f32 -> bf16, 4 elems/thread ----------------
__global__ __launch_bounds__(256) void cast_bf16_kernel(const float* __restrict__ src,
                                                        u16* __restrict__ dst, int n4) {
    int i = blockIdx.x * 256 + threadIdx.x;
    if (i >= n4) return;
    float4 v = ((const float4*)src)[i];
    u64 pk = (u64)f2bf(v.x) | ((u64)f2bf(v.y) << 16) | ((u64)f2bf(v.z) << 32) | ((u64)f2bf(v.w) << 48);
    ((u64*)dst)[i] = pk;
}

// ------------- cast + transpose: src (K x N) f32 -> dst (dstN x K) bf16, zero-pad rows >= N -------------
__global__ __launch_bounds__(256) void cast_transpose(const float* __restrict__ src, u16* __restrict__ dst,
                                                      int K, int N, int dstN) {
    __shared__ float tile[32][33];
    int n0 = blockIdx.x * 32, k0 = blockIdx.y * 32;
    int tx = threadIdx.x & 31, ty = threadIdx.x >> 5;  // 32 x 8
#pragma unroll
    for (int i = 0; i < 4; ++i) {
        int kk = ty + i * 8;
        int n = n0 + tx;
        tile[kk][tx] = (n < N) ? src[(size_t)(k0 + kk) * N + n] : 0.f;
    }
    __syncthreads();
#pragma unroll
    for (int i = 0; i < 4; ++i) {
        int nn = ty + i * 8;
        dst[(size_t)(n0 + nn) * K + k0 + tx] = f2bf(tile[tx][nn]);
    }
}

// ---------------- GEMM (m97 structure): C = A(M x K, lda) * Bt(N x K)^T ----------------
template <int OUTF32>
__global__ __launch_bounds__(256, 2) void gemm_bt(const u16* __restrict__ A, int lda,
                                                  const u16* __restrict__ Bt,
                                                  void* __restrict__ Cv, int ldc, int K) {
    __shared__ u16 As[128 * 32];
    __shared__ u16 Bs[128 * 32];
    const int tid = threadIdx.x;
    const int l = tid & 63, w = tid >> 6;
    const int l15 = l & 15, g = l >> 4;
    const int wr = w >> 1, wc = w & 1;
    const int bm = blockIdx.y * 128, bn = blockIdx.x * 128;

    const f32x4 zero = {0.f, 0.f, 0.f, 0.f};
    f32x4 acc[4][4];
#pragma unroll
    for (int m = 0; m < 4; ++m)
#pragma unroll
        for (int n = 0; n < 4; ++n) acc[m][n] = zero;

    const int ar0 = w * 32 + (l >> 2), kc8 = (l & 3) * 8;
    const u16* aptr = A + (size_t)(bm + ar0) * lda + kc8;
    const u16* aptr2 = A + (size_t)(bm + ar0 + 16) * lda + kc8;
    const u16* bptr = Bt + (size_t)(bn + ar0) * K + kc8;
    const u16* bptr2 = Bt + (size_t)(bn + ar0 + 16) * K + kc8;
    u16* asl = As + w * 1024;
    u16* bsl = Bs + w * 1024;

    const int nK = K / 32;
    for (int kt = 0; kt < nK; ++kt) {
        const int ko = kt * 32;
        __syncthreads();
        gload16(aptr + ko, asl);
        gload16(aptr2 + ko, asl + 512);
        gload16(bptr + ko, bsl);
        gload16(bptr2 + ko, bsl + 512);
        __syncthreads();
        bf16x8 af[4], bfr[4];
#pragma unroll
        for (int m = 0; m < 4; ++m)
            af[m] = ld8(As + (wr * 64 + m * 16 + l15) * 32 + g * 8);
#pragma unroll
        for (int n = 0; n < 4; ++n)
            bfr[n] = ld8(Bs + (wc * 64 + n * 16 + l15) * 32 + g * 8);
#pragma unroll
        for (int m = 0; m < 4; ++m)
#pragma unroll
            for (int n = 0; n < 4; ++n) acc[m][n] = mfma16(af[m], bfr[n], acc[m][n]);
    }
#pragma unroll
    for (int m = 0; m < 4; ++m)
#pragma unroll
        for (int n = 0; n < 4; ++n)
#pragma unroll
            for (int r = 0; r < 4; ++r) {
                int row = bm + wr * 64 + m * 16 + g * 4 + r;
                int col = bn + wc * 64 + n * 16 + l15;
                if (OUTF32)
                    ((float*)Cv)[(size_t)row * ldc + col] = acc[m][n][r];
                else
                    ((u16*)Cv)[(size_t)row * ldc + col] = f2bf(acc[m][n][r]);
            }
}

// ------------- pack: src [BL][2048] (row stride S) -> dst [BL][3072] at h*192 + d (d<128) -------------
__global__ __launch_bounds__(256) void pack_content(const u16* __restrict__ src, int S,
                                                    u16* __restrict__ dst) {
    size_t i = (size_t)blockIdx.x * 256 + threadIdx.x;  // BL*2048/8
    int token = (int)(i >> 8), c = (int)(i & 255);
    int h = c >> 4, d8 = c & 15;
    u32x4 v = *(const u32x4*)(src + (size_t)token * S + c * 8);
    *(u32x4*)(dst + (size_t)token * QKS_ + h * QKD_ + d8 * 8) = v;
}

// ------------- RoPE on q_rope (cols h*64+i at stride S), write into q at h*192+128+i -------------
__global__ __launch_bounds__(256) void rope_q_kernel(const u16* __restrict__ src, int S,
                                                     u16* __restrict__ dst) {
    int idx = blockIdx.x * 256 + threadIdx.x;  // BL*NH*32
    int token = idx >> 9;
    int r = idx & 511;
    int h = r >> 5, i = r & 31;
    int pos = token & (L_ - 1);
    float ang = (float)pos * exp2f((float)i * (-13.287712379549449f / 32.f));
    float c = cosf(ang), s = sinf(ang);
    float x1 = bf2f(src[(size_t)token * S + h * 64 + i]);
    float x2 = bf2f(src[(size_t)token * S + h * 64 + i + 32]);
    u16* base = dst + (size_t)token * QKS_ + h * QKD_ + HD_;
    base[i] = f2bf(x1 * c - x2 * s);
    base[i + 32] = f2bf(x2 * c + x1 * s);
}

// ------------- RoPE on k_rope (64 cols at stride S) + broadcast to all heads of k -------------
__global__ __launch_bounds__(256) void rope_k_kernel(const u16* __restrict__ src, int S,
                                                     u16* __restrict__ dst) {
    int idx = blockIdx.x * 256 + threadIdx.x;  // BL*32
    int token = idx >> 5, i = idx & 31;
    int pos = token & (L_ - 1);
    float ang = (float)pos * exp2f((float)i * (-13.287712379549449f / 32.f));
    float c = cosf(ang), s = sinf(ang);
    float x1 = bf2f(src[(size_t)token * S + i]);
    float x2 = bf2f(src[(size_t)token * S + i + 32]);
    u16 o1 = f2bf(x1 * c - x2 * s);
    u16 o2 = f2bf(x2 * c + x1 * s);
    u16* base = dst + (size_t)token * QKS_ + HD_;
#pragma unroll
    for (int h = 0; h < NH_; ++h) {
        base[h * QKD_ + i] = o1;
        base[h * QKD_ + i + 32] = o2;
    }
}

// ------------- transpose v [BL][*] (stride S) -> vt [(b*2048+col)][L] -------------
__global__ __launch_bounds__(256) void transpose_v(const u16* __restrict__ v, int S,
                                                   u16* __restrict__ vt) {
    __shared__ u16 tile[64][72];
    int cb = blockIdx.x * 64, lb = blockIdx.y * 64, b = blockIdx.z;
    int tid = threadIdx.x;
    int tr = tid >> 3, tc = (tid & 7) * 8;
#pragma unroll
    for (int i = 0; i < 2; ++i) {
        int row = tr + i * 32;
        u32x4 d = *(const u32x4*)(v + (size_t)(b * L_ + lb + row) * S + cb + tc);
        *(u32x4*)&tile[row][tc] = d;
    }
    __syncthreads();
#pragma unroll
    for (int i = 0; i < 2; ++i) {
        int col = tr + i * 32;
        u16 tmp[8];
#pragma unroll
        for (int j = 0; j < 8; ++j) tmp[j] = tile[tc + j][col];
        *(u32x4*)(vt + (size_t)(b * NHHD_ + cb + col) * L_ + lb + tc) = *(u32x4*)tmp;
    }
}

// ------------- causal flash attention, swapped-QK 32x32, paired qtiles, KV-parity split -------------
// grid (16, NH, B): x = p*2+split; block handles qtiles p and 15-p, KV tiles t = split, split+2,...
// -> every block does exactly 17 KV tiles (deterministically balanced), 512 blocks = 2/CU.
// Writes unnormalized partial O (f32) + (m,l) per q-row; combine_attn merges the two splits.
__global__ __launch_bounds__(256, 2) void flash_attn(const u16* __restrict__ q, const u16* __restrict__ k,
                                                     const u16* __restrict__ vt,
                                                     float* __restrict__ opart, float* __restrict__ mlpart) {
    __shared__ __align__(16) u16 Ks[2][64 * 192];   // 2 x 24576 B
    __shared__ __align__(16) u16 Vs[2][128 * 64];   // 2 x 16384 B
    const int p = blockIdx.x >> 1, split = blockIdx.x & 1;
    const int h = blockIdx.y, b = blockIdx.z;
    const int tid = threadIdx.x, w = tid >> 6, l = tid & 63;
    const int ql = l & 31, hi = l >> 5;
    const int sw = ql & 7;

    const u16* kbase = k + (size_t)(b * L_) * QKS_ + h * QKD_;
    const u16* vtbase = vt + (size_t)(b * NHHD_ + h * HD_) * L_;

    // per-lane pre-swizzled global source offsets (elements within a tile)
    int koff[6], voff[4];
#pragma unroll
    for (int j = 0; j < 6; ++j) {
        int off = j * 4096 + tid * 16;
        int row = off / 384;
        int gr = (off % 384) / 16;
        koff[j] = row * QKS_ + (gr ^ (row & 7)) * 8;
    }
#pragma unroll
    for (int j = 0; j < 4; ++j) {
        int off = j * 4096 + tid * 16;
        int row = off >> 7;
        int gr = (off >> 4) & 7;
        voff[j] = row * L_ + (gr ^ (row & 7)) * 8;
    }

    auto STAGE = [&](int buf, int kv0) {
        const u16* kb = kbase + (size_t)kv0 * QKS_;
#pragma unroll
        for (int j = 0; j < 6; ++j)
            gload16(kb + koff[j], (u16*)Ks[buf] + j * 2048 + w * 512);
        const u16* vb = vtbase + kv0;
#pragma unroll
        for (int j = 0; j < 4; ++j)
            gload16(vb + voff[j], (u16*)Vs[buf] + j * 2048 + w * 512);
    };

    for (int half = 0; half < 2; ++half) {
        const int qtile = half ? 15 - p : p;
        const int q0 = qtile * 128;
        const int qabs = q0 + w * 32 + ql;

        bf16x8 qf[12];
        {
            const u16* qrow = q + (size_t)(b * L_ + qabs) * QKS_ + h * QKD_;
#pragma unroll
            for (int c = 0; c < 12; ++c) qf[c] = ld8(qrow + c * 16 + hi * 8);
        }
        f32x16 o[4];
#pragma unroll
        for (int n = 0; n < 4; ++n)
#pragma unroll
            for (int r = 0; r < 16; ++r) o[n][r] = 0.f;
        float m2 = -1e30f, lsum = 0.f;

        const int nt = 2 * qtile + 2;
        __syncthreads();   // all waves done reading LDS from previous half
        STAGE(0, split * 64);
        int i = 0;
        for (int t = split; t < nt; t += 2, ++i) {
            __syncthreads();   // tile t landed, other buf free
            if (t + 2 < nt) STAGE((i + 1) & 1, (t + 2) * 64);
            const u16* Kb = Ks[i & 1];
            const u16* Vb = Vs[i & 1];
            const int kv0 = t * 64;

            // QK^T: S^T[kv][q], two 32-row halves (scores pre-scaled to exp2 domain)
            f32x16 s0, s1;
#pragma unroll
            for (int r = 0; r < 16; ++r) { s0[r] = 0.f; s1[r] = 0.f; }
#pragma unroll
            for (int c = 0; c < 12; ++c) {
                int gsw = ((2 * c + hi) ^ sw) * 16;
                bf16x8 k0 = ld8((const u16*)((const char*)Kb + ql * 384 + gsw));
                bf16x8 k1 = ld8((const u16*)((const char*)Kb + (32 + ql) * 384 + gsw));
                s0 = mfma32(k0, qf[c], s0);
                s1 = mfma32(k1, qf[c], s1);
            }

            // softmax (exp2 domain), lane-local + one cross-half exchange
            const bool domask = (kv0 + 63 > q0);
            float mx = -3e38f;
#pragma unroll
            for (int r = 0; r < 16; ++r) {
                const int kk = (r & 3) + 8 * (r >> 2) + 4 * hi;
                float x0 = s0[r] * SCALE2;
                float x1 = s1[r] * SCALE2;
                if (domask) {
                    if (kv0 + kk > qabs) x0 = -3e38f;
                    if (kv0 + 32 + kk > qabs) x1 = -3e38f;
                }
                s0[r] = x0; s1[r] = x1;
                mx = fmaxf(mx, fmaxf(x0, x1));
            }
            mx = fmaxf(mx, __shfl_xor(mx, 32));
            const float mnew = fmaxf(m2, mx);
            const float f = exp2f(m2 - mnew);
            m2 = mnew;
            float sl = 0.f;
#pragma unroll
            for (int r = 0; r < 16; ++r) {
                float p0 = exp2f(s0[r] - m2);
                float p1 = exp2f(s1[r] - m2);
                s0[r] = p0; s1[r] = p1;
                sl += p0 + p1;
            }
            lsum = lsum * f + sl;
#pragma unroll
            for (int n = 0; n < 4; ++n)
#pragma unroll
                for (int r = 0; r < 16; ++r) o[n][r] *= f;

            // P -> B-fragments via pack + cross-half exchange, then PV (transposed)
#pragma unroll
            for (int c = 0; c < 4; ++c) {
                const int rb = 8 * (c & 1);
                float p0, p1, p2, p3, p4, p5, p6, p7;
                if (c < 2) {
                    p0 = s0[rb + 0]; p1 = s0[rb + 1]; p2 = s0[rb + 2]; p3 = s0[rb + 3];
                    p4 = s0[rb + 4]; p5 = s0[rb + 5]; p6 = s0[rb + 6]; p7 = s0[rb + 7];
                } else {
                    p0 = s1[rb + 0]; p1 = s1[rb + 1]; p2 = s1[rb + 2]; p3 = s1[rb + 3];
                    p4 = s1[rb + 4]; p5 = s1[rb + 5]; p6 = s1[rb + 6]; p7 = s1[rb + 7];
                }
                u32 a0 = pk2(p0, p1), a1 = pk2(p2, p3);
                u32 b0 = pk2(p4, p5), b1 = pk2(p6, p7);
                u32 pa0 = (u32)__shfl_xor((int)a0, 32);
                u32 pa1 = (u32)__shfl_xor((int)a1, 32);
                u32 pb0 = (u32)__shfl_xor((int)b0, 32);
                u32 pb1 = (u32)__shfl_xor((int)b1, 32);
                u32x4 pw = {hi ? pb0 : a0, hi ? pb1 : a1, hi ? b0 : pa0, hi ? b1 : pa1};
                bf16x8 pf = __builtin_bit_cast(bf16x8, pw);
                const int gsw = ((2 * c + hi) ^ sw) * 16;
#pragma unroll
                for (int n = 0; n < 4; ++n) {
                    bf16x8 vf = ld8((const u16*)((const char*)Vb + (32 * n + ql) * 128 + gsw));
                    o[n] = mfma32(vf, pf, o[n]);
                }
            }
        }

        // epilogue: write unnormalized partial O (f32) + (m, l) for this split
        const float ltot = lsum + __shfl_xor(lsum, 32);
        const int row = ((b * NH_ + h) << 11) + qabs;
        float* ob = opart + ((size_t)split * ROWS_ + row) * 128;
#pragma unroll
        for (int n = 0; n < 4; ++n)
#pragma unroll
            for (int rg = 0; rg < 4; ++rg) {
                f32x4 v = {o[n][4 * rg + 0], o[n][4 * rg + 1], o[n][4 * rg + 2], o[n][4 * rg + 3]};
                *(f32x4*)(ob + 32 * n + 8 * rg + 4 * hi) = v;
            }
        if (!hi) {
            float2 ml = {m2, ltot};
            *(float2*)(mlpart + ((size_t)split * ROWS_ + row) * 2) = ml;
        }
    }
}

// ------------- combine the two KV-split partials -> attn_o (bf16) -------------
__global__ __launch_bounds__(256) void combine_attn(const float* __restrict__ opart,
                                                    const float* __restrict__ mlpart,
                                                    u16* __restrict__ attn_o) {
    int idx = blockIdx.x * 256 + threadIdx.x;   // ROWS_*32 threads, 4 d each
    int row = idx >> 5, dq = (idx & 31) * 4;
    float2 ml0 = *(const float2*)(mlpart + (size_t)row * 2);
    float2 ml1 = *(const float2*)(mlpart + ((size_t)ROWS_ + row) * 2);
    float m = fmaxf(ml0.x, ml1.x);
    float w0 = exp2f(ml0.x - m), w1 = exp2f(ml1.x - m);
    float inv = 1.f / (w0 * ml0.y + w1 * ml1.y);
    w0 *= inv; w1 *= inv;
    f32x4 a = *(const f32x4*)(opart + (size_t)row * 128 + dq);
    f32x4 c = *(const f32x4*)(opart + ((size_t)ROWS_ + row) * 128 + dq);
    int b = row >> 15, h = (row >> 11) & 15, qrow = row & 2047;
    u16* dst = attn_o + (size_t)(b * L_ + qrow) * NHHD_ + h * HD_ + dq;
    u64 pk = (u64)pk2(a[0] * w0 + c[0] * w1, a[1] * w0 + c[1] * w1) |
             ((u64)pk2(a[2] * w0 + c[2] * w1, a[3] * w0 + c[3] * w1) << 32);
    *(u64*)dst = pk;
}

extern "C" void kernel_launch(void* const* d_in, const int* in_sizes, int n_in,
                              void* d_out, int out_size, void* d_ws, size_t ws_size,
                              hipStream_t stream) {
    (void)in_sizes; (void)n_in; (void)out_size; (void)ws_size;
    const float* x = (const float*)d_in[0];
    const float* wq_down = (const float*)d_in[1];
    const float* wq_up = (const float*)d_in[2];
    const float* wq_rope = (const float*)d_in[3];
    const float* wkv_down = (const float*)d_in[4];
    const float* wk_up = (const float*)d_in[5];
    const float* wv_up = (const float*)d_in[6];
    const float* wk_rope = (const float*)d_in[7];
    const float* wo = (const float*)d_in[8];

    u16* W = (u16*)d_ws;
    size_t off = 0;
    auto alloc = [&](size_t e) { u16* p = W + off; off += (e + 127) & ~(size_t)127; return p; };

    u16* xb    = alloc((size_t)BL_ * H_);        // 4096 x 2048
    u16* Wdn   = alloc((size_t)1408 * H_);       // [768 qd | 512 kvd | 128 kr(pad)] x 2048
    u16* Wupq  = alloc((size_t)3072 * QR_);      // [2048 qu | 1024 qr] x 768
    u16* Wupkv = alloc((size_t)4096 * KVR_);     // [2048 ku | 2048 vu] x 512
    u16* Wo_t  = alloc((size_t)H_ * NHHD_);      // 2048 x 2048
    u16* C1    = alloc((size_t)BL_ * 1408);      // latents: q_lat | kv_lat | k_rope_raw
    u16* C2    = alloc((size_t)BL_ * 3072);      // q_content | q_rope_raw
    u16* C3    = alloc((size_t)BL_ * 4096);      // k_content | v
    u16* qbuf  = alloc((size_t)BL_ * QKS_);
    u16* kbuf  = alloc((size_t)BL_ * QKS_);
    u16* vt    = alloc((size_t)BL_ * NHHD_);
    u16* attn_o = alloc((size_t)BL_ * NHHD_);

    // attention partials alias the dead C1|C2|C3 span (35.1M u16 = 70.3 MB >= 68.2 MB needed):
    // C1..C3 are fully consumed before flash_attn launches.
    float* opart  = (float*)C1;                          // 2 * 65536 rows * 128 f32 = 67.1 MB
    float* mlpart = opart + (size_t)2 * ROWS_ * 128;     // 2 * 65536 * 2 f32 = 1.05 MB

    // 1. casts + fused weight transposes
    cast_bf16_kernel<<<(BL_ * H_ / 4 + 255) / 256, 256, 0, stream>>>(x, xb, BL_ * H_ / 4);
    cast_transpose<<<dim3(QR_ / 32, H_ / 32), 256, 0, stream>>>(wq_down, Wdn, H_, QR_, QR_);
    cast_transpose<<<dim3(KVR_ / 32, H_ / 32), 256, 0, stream>>>(wkv_down, Wdn + (size_t)768 * H_, H_, KVR_, KVR_);
    cast_transpose<<<dim3(128 / 32, H_ / 32), 256, 0, stream>>>(wk_rope, Wdn + (size_t)1280 * H_, H_, RD_, 128);
    cast_transpose<<<dim3(NHHD_ / 32, QR_ / 32), 256, 0, stream>>>(wq_up, Wupq, QR_, NHHD_, NHHD_);
    cast_transpose<<<dim3(1024 / 32, QR_ / 32), 256, 0, stream>>>(wq_rope, Wupq + (size_t)2048 * QR_, QR_, 1024, 1024);
    cast_transpose<<<dim3(NHHD_ / 32, KVR_ / 32), 256, 0, stream>>>(wk_up, Wupkv, KVR_, NHHD_, NHHD_);
    cast_transpose<<<dim3(NHHD_ / 32, KVR_ / 32), 256, 0, stream>>>(wv_up, Wupkv + (size_t)2048 * KVR_, KVR_, NHHD_, NHHD_);
    cast_transpose<<<dim3(NHHD_ / 32, H_ / 32), 256, 0, stream>>>(wo, Wo_t, NHHD_, H_, H_);

    // 2. fused projection GEMMs
    gemm_bt<0><<<dim3(1408 / 128, BL_ / 128), 256, 0, stream>>>(xb, H_, Wdn, C1, 1408, H_);
    gemm_bt<0><<<dim3(3072 / 128, BL_ / 128), 256, 0, stream>>>(C1, 1408, Wupq, C2, 3072, QR_);
    gemm_bt<0><<<dim3(4096 / 128, BL_ / 128), 256, 0, stream>>>(C1 + 768, 1408, Wupkv, C3, 4096, KVR_);

    // 3. assemble q, k, vt
    pack_content<<<BL_ * NHHD_ / 8 / 256, 256, 0, stream>>>(C2, 3072, qbuf);
    pack_content<<<BL_ * NHHD_ / 8 / 256, 256, 0, stream>>>(C3, 4096, kbuf);
    rope_q_kernel<<<BL_ * NH_ * 32 / 256, 256, 0, stream>>>(C2 + 2048, 3072, qbuf);
    rope_k_kernel<<<BL_ * 32 / 256, 256, 0, stream>>>(C1 + 1280, 1408, kbuf);
    transpose_v<<<dim3(NHHD_ / 64, L_ / 64, B_), 256, 0, stream>>>(C3 + 2048, 4096, vt);

    // 4. attention: KV-parity split (512 balanced blocks, 2/CU), then combine
    flash_attn<<<dim3(16, NH_, B_), 256, 0, stream>>>(qbuf, kbuf, vt, opart, mlpart);
    combine_attn<<<ROWS_ * 32 / 256, 256, 0, stream>>>(opart, mlpart, attn_o);

    // 5. output projection (fp32 out)
    gemm_bt<1><<<dim3(H_ / 128, BL_ / 128), 256, 0, stream>>>(attn_o, NHHD_, Wo_t, d_out, H_, NHHD_);
}